// Round 2
// baseline (1973.803 us; speedup 1.0000x reference)
//
#include <hip/hip_runtime.h>

// VQ nearest-codebook, replicating the numpy FLOAT32 reference pipeline
// bit-exactly (d values quantize at ulp(256)=3e-5, ties broken by first
// index -- an exact-arithmetic argmin does NOT match it).
//
// numpy semantics replicated:
//  - cross = np.einsum('nd,kd->nk'): SSE-baseline npyv dot kernel: 4 f32
//    lanes, one accumulator, chunks of 16 with reversed muladd chaining
//    s' = p0+(p1+(p2+(p3+s))) per lane, mul/add separately rounded,
//    reduce (s0+s1)+(s2+s3).
//  - row norms = np.sum(x*x, axis=1): pairwise_sum: 256 -> 128+128, each
//    128-block = 8 mod-8 scalar accumulators, combine
//    ((r0+r1)+(r2+r3))+((r4+r5)+(r6+r7)).
//  - d = fl(fl(zn+en) - fl(2*cross)); argmin first-index tie-break.
//
// ws: zt 16MB | znorm 64KB | enorm 64KB | part 8MB  (~24.2 MB total)

#define NQ 16384
#define NE 16384
#define DIM 256

__device__ __forceinline__ float fm(float a, float b) { return __fmul_rn(a, b); }
__device__ __forceinline__ float fa(float a, float b) { return __fadd_rn(a, b); }
__device__ __forceinline__ float fs(float a, float b) { return __fsub_rn(a, b); }

// ---------------- transpose z[b][c][hw] -> zt[b*1024+hw][c] ----------------
__global__ void transpose_z(const float* __restrict__ z, float* __restrict__ zt) {
    __shared__ float tile[32][33];
    const int b  = blockIdx.z;
    const int c0 = blockIdx.y * 32;
    const int n0 = blockIdx.x * 32;
    const int tx = threadIdx.x;      // 0..31
    const int ty = threadIdx.y;      // 0..7
    const float* zb = z + (size_t)b * 256 * 1024;
    #pragma unroll
    for (int j = 0; j < 32; j += 8)
        tile[ty + j][tx] = zb[(size_t)(c0 + ty + j) * 1024 + n0 + tx];
    __syncthreads();
    float* ztb = zt + (size_t)b * 1024 * 256;
    #pragma unroll
    for (int j = 0; j < 32; j += 8)
        ztb[(size_t)(n0 + ty + j) * 256 + c0 + tx] = tile[tx][ty + j];
}

// ------------- numpy pairwise_sum(x*x) over a 256-float row -------------
__global__ __launch_bounds__(256) void row_norms_np(const float* __restrict__ x,
                                                    float* __restrict__ out) {
    const int row = blockIdx.x * 256 + threadIdx.x;
    const float* p = x + (size_t)row * DIM;
    float half_[2];
    #pragma unroll
    for (int h = 0; h < 2; ++h) {
        const float* q = p + h * 128;
        float r[8];
        #pragma unroll
        for (int j = 0; j < 8; j++) r[j] = fm(q[j], q[j]);
        #pragma unroll
        for (int i = 8; i < 128; i += 8)
            #pragma unroll
            for (int j = 0; j < 8; j++) r[j] = fa(r[j], fm(q[i + j], q[i + j]));
        half_[h] = fa(fa(fa(r[0], r[1]), fa(r[2], r[3])),
                      fa(fa(r[4], r[5]), fa(r[6], r[7])));
    }
    out[row] = fa(half_[0], half_[1]);
}

// ------ fused distance tiles + partial argmin (numpy-f32-exact) ------
// grid (256 row-tiles, 64 col-groups); each block: 64 rows x 256 cols
// (4 subtiles of 64), part[row][colgroup] = {d, idx}.
__global__ __launch_bounds__(256) void dist_argmin_np(
    const float* __restrict__ zt, const float* __restrict__ cb,
    const float* __restrict__ znorm, const float* __restrict__ enorm,
    float2* __restrict__ part)
{
    __shared__ float Asub[64][68];
    __shared__ float Bsub[64][68];
    const int t  = threadIdx.x;
    const int tx = t & 15, ty = t >> 4;          // 16x16
    const int m0  = blockIdx.x * 64;
    const int nb0 = blockIdx.y * 256;

    float zn[4];
    #pragma unroll
    for (int i = 0; i < 4; i++) zn[i] = znorm[m0 + ty + 16 * i];

    float bestS[4]; int bestI[4];
    #pragma unroll
    for (int i = 0; i < 4; i++) { bestS[i] = 3.4e38f; bestI[i] = 0x7fffffff; }

    for (int sub = 0; sub < 4; ++sub) {
        const int n0 = nb0 + sub * 64;
        // s[i][j][l]: einsum SIMD lane accumulators (lane l = dim mod 4)
        float s[4][4][4];
        #pragma unroll
        for (int i = 0; i < 4; i++)
            #pragma unroll
            for (int j = 0; j < 4; j++)
                #pragma unroll
                for (int l = 0; l < 4; l++) s[i][j][l] = 0.0f;

        for (int kc = 0; kc < 4; ++kc) {
            const int kk = kc * 64;
            #pragma unroll
            for (int p = 0; p < 4; ++p) {
                const int f   = t + p * 256;
                const int row = f >> 4;
                const int c4  = f & 15;
                *(float4*)&Asub[row][c4 * 4] =
                    *(const float4*)(zt + (size_t)(m0 + row) * DIM + kk + c4 * 4);
                *(float4*)&Bsub[row][c4 * 4] =
                    *(const float4*)(cb + (size_t)(n0 + row) * DIM + kk + c4 * 4);
            }
            __syncthreads();
            #pragma unroll
            for (int ch = 0; ch < 4; ++ch) {       // 16-dim chunks, ascending
                const int c16 = ch * 16;
                #pragma unroll
                for (int v = 3; v >= 0; --v) {     // reversed muladd chaining
                    float4 a4[4], b4[4];
                    #pragma unroll
                    for (int i = 0; i < 4; i++)
                        a4[i] = *(const float4*)&Asub[ty + 16 * i][c16 + 4 * v];
                    #pragma unroll
                    for (int j = 0; j < 4; j++)
                        b4[j] = *(const float4*)&Bsub[tx + 16 * j][c16 + 4 * v];
                    #pragma unroll
                    for (int i = 0; i < 4; i++)
                        #pragma unroll
                        for (int j = 0; j < 4; j++) {
                            s[i][j][0] = fa(fm(a4[i].x, b4[j].x), s[i][j][0]);
                            s[i][j][1] = fa(fm(a4[i].y, b4[j].y), s[i][j][1]);
                            s[i][j][2] = fa(fm(a4[i].z, b4[j].z), s[i][j][2]);
                            s[i][j][3] = fa(fm(a4[i].w, b4[j].w), s[i][j][3]);
                        }
                }
            }
            __syncthreads();
        }
        // epilogue: cross = (s0+s1)+(s2+s3); d = fl(fl(zn+en) - 2*cross)
        #pragma unroll
        for (int j = 0; j < 4; j++) {
            const int col = n0 + tx + 16 * j;
            const float en = enorm[col];
            #pragma unroll
            for (int i = 0; i < 4; i++) {
                const float cr = fa(fa(s[i][j][0], s[i][j][1]),
                                    fa(s[i][j][2], s[i][j][3]));
                const float d  = fs(fa(zn[i], en), fm(2.0f, cr));
                if (d < bestS[i] || (d == bestS[i] && col < bestI[i])) {
                    bestS[i] = d; bestI[i] = col;
                }
            }
        }
    }

    __syncthreads();
    float* red_s = &Asub[0][0];          // 64*16 floats
    int*   red_i = (int*)&Bsub[0][0];
    #pragma unroll
    for (int i = 0; i < 4; i++) {
        const int row = ty + 16 * i;
        red_s[row * 16 + tx] = bestS[i];
        red_i[row * 16 + tx] = bestI[i];
    }
    __syncthreads();
    if (t < 64) {
        float bs = red_s[t * 16]; int bi = red_i[t * 16];
        #pragma unroll
        for (int x = 1; x < 16; x++) {
            const float s2 = red_s[t * 16 + x]; const int i2 = red_i[t * 16 + x];
            if (s2 < bs || (s2 == bs && i2 < bi)) { bs = s2; bi = i2; }
        }
        part[(size_t)(m0 + t) * 64 + blockIdx.y] = make_float2(bs, __int_as_float(bi));
    }
}

// ---------------- final reduce over 64 col-groups + gather z_q ----------------
__global__ __launch_bounds__(256) void final_reduce_np(
    const float2* __restrict__ part, const float* __restrict__ cb,
    float* __restrict__ out_zq, float* __restrict__ out_idx)
{
    const int m = blockIdx.x;
    const int t = threadIdx.x;
    __shared__ float ss[64];
    __shared__ int   si[64];
    if (t < 64) {
        const float2 p = part[(size_t)m * 64 + t];
        ss[t] = p.x; si[t] = __float_as_int(p.y);
    }
    __syncthreads();
    for (int off = 32; off; off >>= 1) {
        if (t < off) {
            const float s2 = ss[t + off]; const int i2 = si[t + off];
            if (s2 < ss[t] || (s2 == ss[t] && i2 < si[t])) { ss[t] = s2; si[t] = i2; }
        }
        __syncthreads();
    }
    const int idx = si[0];
    out_zq[(size_t)m * DIM + t] = cb[(size_t)idx * DIM + t];
    if (t == 0) out_idx[m] = (float)idx;
}

extern "C" void kernel_launch(void* const* d_in, const int* in_sizes, int n_in,
                              void* d_out, int out_size, void* d_ws, size_t ws_size,
                              hipStream_t stream) {
    const float* z  = (const float*)d_in[0];   // [16][256][32][32]
    const float* cb = (const float*)d_in[1];   // [16384][256]
    float* out = (float*)d_out;                // z_q (4194304 f32) then idx (16384 as f32)

    char* ws = (char*)d_ws;
    float*  zt    = (float*)ws;                                    // 16 MB
    float*  znorm = (float*)(ws + (size_t)16777216);               // 64 KB
    float*  enorm = (float*)(ws + (size_t)16777216 + 65536);       // 64 KB
    float2* part  = (float2*)(ws + (size_t)16777216 + 131072);     // 8 MB

    transpose_z<<<dim3(32, 8, 16), dim3(32, 8), 0, stream>>>(z, zt);
    row_norms_np<<<NQ / 256, 256, 0, stream>>>(zt, znorm);
    row_norms_np<<<NE / 256, 256, 0, stream>>>(cb, enorm);
    dist_argmin_np<<<dim3(NQ / 64, NE / 256), 256, 0, stream>>>(zt, cb, znorm, enorm, part);
    final_reduce_np<<<NQ, 256, 0, stream>>>(part, cb, out, out + (size_t)NQ * DIM);
}

// Round 3
// 789.729 us; speedup vs baseline: 2.4993x; 2.4993x over previous
//
#include <hip/hip_runtime.h>

// VQ nearest-codebook. Reference semantics = numpy float32 pipeline (verified
// bit-exact in round 2). Strategy now: bf16-split MFMA GEMM for approximate
// scores s = en - 2*z.e  (error ~1e-6), per-row top-3 keys per 512-col group,
// then exact numpy-f32 re-score of the few candidates within the reference's
// rounding slack (6.1e-5 -> 72 quantized units at 2^-20).
//
// ws: zhi 8MB | zlo 8MB | ehi 8MB | elo 8MB | zn 64KB | en 64KB | part 6.3MB

#define NQ 16384
#define NE 16384
#define DIM 256

typedef __attribute__((ext_vector_type(8))) short short8;
typedef __attribute__((ext_vector_type(4))) float floatx4;

__device__ __forceinline__ float fm(float a, float b) { return __fmul_rn(a, b); }
__device__ __forceinline__ float fa(float a, float b) { return __fadd_rn(a, b); }
__device__ __forceinline__ float fs(float a, float b) { return __fsub_rn(a, b); }

// manual RNE float->bf16 (no NaN in this data)
__device__ __forceinline__ unsigned short f2bf(float v) {
    unsigned u = __float_as_uint(v);
    return (unsigned short)((u + 0x7FFFu + ((u >> 16) & 1u)) >> 16);
}

// ---------- split+transpose z[b][c][hw] -> zhi/zlo[(b*1024+hw)][c] ----------
__global__ void split_z(const float* __restrict__ z,
                        unsigned short* __restrict__ zhi,
                        unsigned short* __restrict__ zlo) {
    __shared__ float tile[32][33];
    const int b  = blockIdx.z;
    const int c0 = blockIdx.y * 32;
    const int n0 = blockIdx.x * 32;
    const int tx = threadIdx.x, ty = threadIdx.y;   // 32 x 8
    const float* zb = z + (size_t)b * 256 * 1024;
    #pragma unroll
    for (int j = 0; j < 32; j += 8)
        tile[ty + j][tx] = zb[(size_t)(c0 + ty + j) * 1024 + n0 + tx];
    __syncthreads();
    #pragma unroll
    for (int j = 0; j < 32; j += 8) {
        const float v = tile[tx][ty + j];
        const unsigned short h = f2bf(v);
        const float hf = __uint_as_float((unsigned)h << 16);
        const unsigned short l = f2bf(v - hf);
        const size_t o = (size_t)(b * 1024 + n0 + ty + j) * 256 + c0 + tx;
        zhi[o] = h; zlo[o] = l;
    }
}

// ---------------- split codebook -> ehi/elo ----------------
__global__ __launch_bounds__(256) void split_e(const float* __restrict__ cb,
                                               unsigned short* __restrict__ ehi,
                                               unsigned short* __restrict__ elo) {
    const size_t i = ((size_t)blockIdx.x * 256 + threadIdx.x) * 4;
    const float4 v = *(const float4*)(cb + i);
    ushort4 h, l;
    h.x = f2bf(v.x); l.x = f2bf(v.x - __uint_as_float((unsigned)h.x << 16));
    h.y = f2bf(v.y); l.y = f2bf(v.y - __uint_as_float((unsigned)h.y << 16));
    h.z = f2bf(v.z); l.z = f2bf(v.z - __uint_as_float((unsigned)h.z << 16));
    h.w = f2bf(v.w); l.w = f2bf(v.w - __uint_as_float((unsigned)h.w << 16));
    *(ushort4*)(ehi + i) = h;
    *(ushort4*)(elo + i) = l;
}

// ------------- numpy pairwise_sum(x*x) over 256 contiguous floats -------------
__global__ __launch_bounds__(256) void row_norms_np(const float* __restrict__ x,
                                                    float* __restrict__ out) {
    const int row = blockIdx.x * 256 + threadIdx.x;
    const float* p = x + (size_t)row * DIM;
    float half_[2];
    #pragma unroll
    for (int h = 0; h < 2; ++h) {
        const float* q = p + h * 128;
        float r[8];
        #pragma unroll
        for (int j = 0; j < 8; j++) r[j] = fm(q[j], q[j]);
        #pragma unroll
        for (int i = 8; i < 128; i += 8)
            #pragma unroll
            for (int j = 0; j < 8; j++) r[j] = fa(r[j], fm(q[i + j], q[i + j]));
        half_[h] = fa(fa(fa(r[0], r[1]), fa(r[2], r[3])),
                      fa(fa(r[4], r[5]), fa(r[6], r[7])));
    }
    out[row] = fa(half_[0], half_[1]);
}

// ------------- same, over a strided z row: element c at z[b][c][hw] -------------
__global__ __launch_bounds__(256) void znorm_np_z(const float* __restrict__ z,
                                                  float* __restrict__ out) {
    const int row = blockIdx.x * 256 + threadIdx.x;
    const float* p = z + ((size_t)(row >> 10) * 256) * 1024 + (row & 1023);
    float half_[2];
    #pragma unroll
    for (int h = 0; h < 2; ++h) {
        const int c0 = h * 128;
        float r[8], v;
        #pragma unroll
        for (int j = 0; j < 8; j++) { v = p[(size_t)(c0 + j) << 10]; r[j] = fm(v, v); }
        #pragma unroll
        for (int i = 8; i < 128; i += 8)
            #pragma unroll
            for (int j = 0; j < 8; j++) {
                v = p[(size_t)(c0 + i + j) << 10];
                r[j] = fa(r[j], fm(v, v));
            }
        half_[h] = fa(fa(fa(r[0], r[1]), fa(r[2], r[3])),
                      fa(fa(r[4], r[5]), fa(r[6], r[7])));
    }
    out[row] = fa(half_[0], half_[1]);
}

// sorted-triple merge: (a,b sorted ascending) -> top-3 of union in a
__device__ __forceinline__ void merge3(unsigned& a0, unsigned& a1, unsigned& a2,
                                       unsigned b0, unsigned b1, unsigned b2) {
    const unsigned m0 = min(a0, b0);
    const unsigned x  = max(a0, b0);
    const unsigned p  = min(a1, b1);
    const unsigned q  = max(a1, b1);
    const unsigned m1 = min(x, p);
    const unsigned m2 = min(max(x, p), min(q, min(a2, b2)));
    a0 = m0; a1 = m1; a2 = m2;
}

// ---------------- MFMA GEMM (K=768 bf16-split) + per-row top-3 keys ----------------
// grid (128 row-tiles, 32 col-groups of 512); block 256 = 4 waves (2x2 of 64x64)
__global__ __launch_bounds__(256) void gemm_top3(
    const unsigned short* __restrict__ zhi, const unsigned short* __restrict__ zlo,
    const unsigned short* __restrict__ ehi, const unsigned short* __restrict__ elo,
    const float* __restrict__ en, unsigned* __restrict__ part)
{
    __shared__ unsigned short Ab[128 * 64];   // [m][g'] g' = g ^ (m&7), 16B groups
    __shared__ unsigned short Bb[128 * 64];
    __shared__ unsigned mbuf[128 * 8 * 3];    // per-row sorted top3 x (wc*4+sub)

    const int t = threadIdx.x;
    const int lane = t & 63, w = t >> 6;
    const int wr = w >> 1, wc = w & 1;
    const int q4 = lane >> 4, c4 = lane & 15;
    const int m0 = blockIdx.x * 128;
    const int g0 = blockIdx.y * 512;

    for (int sub = 0; sub < 4; ++sub) {
        const int n0 = g0 + sub * 128;
        floatx4 acc[4][4];
        #pragma unroll
        for (int i = 0; i < 4; i++)
            #pragma unroll
            for (int j = 0; j < 4; j++) acc[i][j] = (floatx4){0.f, 0.f, 0.f, 0.f};

        for (int kc = 0; kc < 12; ++kc) {
            const int ph = kc >> 2;
            const int kb = (kc & 3) * 64;
            const unsigned short* Ag = (ph == 2) ? zlo : zhi;
            const unsigned short* Bg = (ph == 1) ? elo : ehi;
            #pragma unroll
            for (int p = 0; p < 4; ++p) {
                const int s   = p * 256 + t;
                const int m   = s >> 3;
                const int gsw = s & 7;
                const int g   = gsw ^ (m & 7);
                const int4 av = *(const int4*)(Ag + (size_t)(m0 + m) * 256 + kb + g * 8);
                const int4 bv = *(const int4*)(Bg + (size_t)(n0 + m) * 256 + kb + g * 8);
                *(int4*)&Ab[(size_t)s * 8] = av;
                *(int4*)&Bb[(size_t)s * 8] = bv;
            }
            __syncthreads();
            #pragma unroll
            for (int kk = 0; kk < 2; ++kk) {
                short8 a[4], b[4];
                #pragma unroll
                for (int i = 0; i < 4; ++i) {
                    const int m  = wr * 64 + i * 16 + c4;
                    const int gs = (kk * 4 + q4) ^ (m & 7);
                    a[i] = *(const short8*)&Ab[(size_t)(m * 8 + gs) * 8];
                }
                #pragma unroll
                for (int j = 0; j < 4; ++j) {
                    const int n  = wc * 64 + j * 16 + c4;
                    const int gs = (kk * 4 + q4) ^ (n & 7);
                    b[j] = *(const short8*)&Bb[(size_t)(n * 8 + gs) * 8];
                }
                #pragma unroll
                for (int i = 0; i < 4; ++i)
                    #pragma unroll
                    for (int j = 0; j < 4; ++j)
                        acc[i][j] = __builtin_amdgcn_mfma_f32_16x16x32_bf16(
                            a[i], b[j], acc[i][j], 0, 0, 0);
            }
            __syncthreads();
        }

        // ---- epilogue: keys + per-row top-3 over this sub's 128 cols ----
        float enj[4];
        #pragma unroll
        for (int j = 0; j < 4; ++j) enj[j] = en[n0 + wc * 64 + j * 16 + c4];

        #pragma unroll
        for (int i = 0; i < 4; ++i) {
            #pragma unroll
            for (int r = 0; r < 4; ++r) {
                unsigned k[4];
                #pragma unroll
                for (int j = 0; j < 4; ++j) {
                    const float s = __builtin_fmaf(-2.0f, acc[i][j][r], enj[j]);
                    int v = (int)rintf(s * 1048576.0f);
                    v = min(max(v, -131072), 131071);
                    k[j] = ((unsigned)(v + 131072) << 14) |
                           (unsigned)(n0 + wc * 64 + j * 16 + c4);
                }
                // sort4 -> ascending top-3
                unsigned lo, hi;
                lo = min(k[0], k[1]); hi = max(k[0], k[1]); k[0] = lo; k[1] = hi;
                lo = min(k[2], k[3]); hi = max(k[2], k[3]); k[2] = lo; k[3] = hi;
                lo = min(k[0], k[2]); hi = max(k[0], k[2]); k[0] = lo; k[2] = hi;
                lo = min(k[1], k[3]); k[1] = lo;
                lo = min(k[1], k[2]); hi = max(k[1], k[2]); k[1] = lo; k[2] = hi;
                unsigned t0 = k[0], t1 = k[1], t2 = k[2];
                #pragma unroll
                for (int msk = 1; msk < 16; msk <<= 1) {
                    const unsigned u0 = (unsigned)__shfl_xor((int)t0, msk, 64);
                    const unsigned u1 = (unsigned)__shfl_xor((int)t1, msk, 64);
                    const unsigned u2 = (unsigned)__shfl_xor((int)t2, msk, 64);
                    merge3(t0, t1, t2, u0, u1, u2);
                }
                if (c4 < 3) {
                    const int row = wr * 64 + i * 16 + q4 * 4 + r;
                    const unsigned val = (c4 == 0) ? t0 : (c4 == 1 ? t1 : t2);
                    mbuf[(row * 8 + wc * 4 + sub) * 3 + c4] = val;
                }
            }
        }
    }

    __syncthreads();
    if (t < 128) {
        unsigned t0 = mbuf[(t * 8 + 0) * 3 + 0];
        unsigned t1 = mbuf[(t * 8 + 0) * 3 + 1];
        unsigned t2 = mbuf[(t * 8 + 0) * 3 + 2];
        #pragma unroll
        for (int s = 1; s < 8; ++s)
            merge3(t0, t1, t2, mbuf[(t * 8 + s) * 3 + 0],
                   mbuf[(t * 8 + s) * 3 + 1], mbuf[(t * 8 + s) * 3 + 2]);
        unsigned* pp = part + (size_t)(m0 + t) * 96 + blockIdx.y * 3;
        pp[0] = t0; pp[1] = t1; pp[2] = t2;
    }
}

// ---------------- resolve: window-candidates -> exact numpy re-score ----------------
__global__ __launch_bounds__(256) void resolve(
    const unsigned* __restrict__ part, const float* __restrict__ z,
    const float* __restrict__ cb, const float* __restrict__ zn,
    const float* __restrict__ en, float* __restrict__ out_zq,
    float* __restrict__ out_idx)
{
    const int w = threadIdx.x >> 6, lane = threadIdx.x & 63;
    const int row = blockIdx.x * 4 + w;
    __shared__ unsigned candbuf[4][16];

    const unsigned* pr = part + (size_t)row * 96;
    const unsigned k1 = pr[lane];
    const unsigned k2 = (lane < 32) ? pr[64 + lane] : 0xFFFFFFFFu;
    unsigned vm = min(k1, k2);
    #pragma unroll
    for (int m = 1; m < 64; m <<= 1)
        vm = min(vm, (unsigned)__shfl_xor((int)vm, m, 64));
    const unsigned vlim = (vm >> 14) + 72u;
    const bool s1 = (k1 >> 14) <= vlim;
    const bool s2 = (lane < 32) && ((k2 >> 14) <= vlim);
    const unsigned long long b1 = __ballot(s1);
    const unsigned long long b2 = __ballot(s2);
    const unsigned long long below = (1ull << lane) - 1ull;
    const int pos1 = __popcll(b1 & below);
    const int pos2 = __popcll(b1) + __popcll(b2 & below);
    int ncand = __popcll(b1) + __popcll(b2);
    if (ncand > 16) ncand = 16;

    if (lane < 16) candbuf[w][lane] = 0;
    __syncthreads();
    if (s1 && pos1 < 16) candbuf[w][pos1] = k1 & 16383u;
    if (s2 && pos2 < 16) candbuf[w][pos2] = k2 & 16383u;
    __syncthreads();

    const int ci = lane >> 2, l = lane & 3;
    const bool act = ci < ncand;
    const unsigned idxc = candbuf[w][ci];
    const float* zb  = z + ((size_t)(row >> 10) * 256) * 1024 + (row & 1023);
    const float* cbr = cb + (size_t)idxc * 256;
    // numpy einsum SSE chain, lane l of 4: elements ch*16 + v*4 + l, v desc
    float s = 0.f;
    #pragma unroll
    for (int ch = 0; ch < 16; ++ch)
        #pragma unroll
        for (int v = 3; v >= 0; --v) {
            const int cd = ch * 16 + v * 4 + l;
            s = fa(fm(zb[(size_t)cd << 10], cbr[cd]), s);
        }
    const int base = lane & ~3;
    const float s0 = __shfl(s, base + 0, 64);
    const float sA = __shfl(s, base + 1, 64);
    const float sB = __shfl(s, base + 2, 64);
    const float sC = __shfl(s, base + 3, 64);
    const float cross = fa(fa(s0, sA), fa(sB, sC));
    const float d = fs(fa(zn[row], en[idxc]), fm(2.0f, cross));
    unsigned long long key = act
        ? (((unsigned long long)__float_as_uint(d) << 32) | idxc) : ~0ull;
    #pragma unroll
    for (int m = 1; m < 64; m <<= 1) {
        const unsigned long long o =
            (unsigned long long)__shfl_xor((long long)key, m, 64);
        if (o < key) key = o;
    }
    const int widx = (int)(key & 0xFFFFFFFFu);
    *(float4*)(out_zq + (size_t)row * 256 + lane * 4) =
        *(const float4*)(cb + (size_t)widx * 256 + lane * 4);
    if (lane == 0) out_idx[row] = (float)widx;
}

extern "C" void kernel_launch(void* const* d_in, const int* in_sizes, int n_in,
                              void* d_out, int out_size, void* d_ws, size_t ws_size,
                              hipStream_t stream) {
    const float* z  = (const float*)d_in[0];   // [16][256][32][32]
    const float* cb = (const float*)d_in[1];   // [16384][256]
    float* out = (float*)d_out;                // z_q (4194304 f32) then idx (16384 as f32)

    char* ws = (char*)d_ws;
    unsigned short* zhi = (unsigned short*)ws;                        // 8 MB
    unsigned short* zlo = (unsigned short*)(ws + (size_t)8388608);    // 8 MB
    unsigned short* ehi = (unsigned short*)(ws + (size_t)16777216);   // 8 MB
    unsigned short* elo = (unsigned short*)(ws + (size_t)25165824);   // 8 MB
    float* zn  = (float*)(ws + (size_t)33554432);                     // 64 KB
    float* en  = (float*)(ws + (size_t)33619968);                     // 64 KB
    unsigned* part = (unsigned*)(ws + (size_t)33685504);              // 6.29 MB

    split_z<<<dim3(32, 8, 16), dim3(32, 8), 0, stream>>>(z, zhi, zlo);
    split_e<<<4096, 256, 0, stream>>>(cb, ehi, elo);
    znorm_np_z<<<NQ / 256, 256, 0, stream>>>(z, zn);
    row_norms_np<<<NE / 256, 256, 0, stream>>>(cb, en);
    gemm_top3<<<dim3(128, 32), 256, 0, stream>>>(zhi, zlo, ehi, elo, en, part);
    resolve<<<4096, 256, 0, stream>>>(part, z, cb, zn, en, out,
                                      out + (size_t)NQ * DIM);
}

// Round 4
// 676.128 us; speedup vs baseline: 2.9193x; 1.1680x over previous
//
#include <hip/hip_runtime.h>

// VQ nearest-codebook. Reference = numpy float32 pipeline (verified bit-exact
// R2). bf16 MFMA GEMM computes approx scores s = en - 2*zhi.(ehi+elo) (K=512;
// omitted zlo.e term ~4e-6 worst-case), per-row running top-3 keys per
// 512-col group, exact numpy-f32 re-score of window candidates (84 units at
// 2^-20 covers ref rounding slack 6.1e-5 + GEMM/quant error).
//
// ws: zhi 8MB | ehi 8MB | elo 8MB | zn 64K | en 64K | part 6.3MB

#define NQ 16384
#define NE 16384
#define DIM 256

typedef __attribute__((ext_vector_type(8))) short short8;
typedef __attribute__((ext_vector_type(4))) float floatx4;

__device__ __forceinline__ float fm(float a, float b) { return __fmul_rn(a, b); }
__device__ __forceinline__ float fa(float a, float b) { return __fadd_rn(a, b); }
__device__ __forceinline__ float fs(float a, float b) { return __fsub_rn(a, b); }

__device__ __forceinline__ unsigned short f2bf(float v) {
    unsigned u = __float_as_uint(v);
    return (unsigned short)((u + 0x7FFFu + ((u >> 16) & 1u)) >> 16);
}

// ---------- transpose z[b][c][hw] -> zhi[(b*1024+hw)][c] (bf16 hi) ----------
__global__ void split_z(const float* __restrict__ z, unsigned short* __restrict__ zhi) {
    __shared__ float tile[32][33];
    const int b  = blockIdx.z;
    const int c0 = blockIdx.y * 32;
    const int n0 = blockIdx.x * 32;
    const int tx = threadIdx.x, ty = threadIdx.y;   // 32 x 8
    const float* zb = z + (size_t)b * 256 * 1024;
    #pragma unroll
    for (int j = 0; j < 32; j += 8)
        tile[ty + j][tx] = zb[(size_t)(c0 + ty + j) * 1024 + n0 + tx];
    __syncthreads();
    #pragma unroll
    for (int j = 0; j < 32; j += 8) {
        const float v = tile[tx][ty + j];
        zhi[(size_t)(b * 1024 + n0 + ty + j) * 256 + c0 + tx] = f2bf(v);
    }
}

// ---------------- split codebook -> ehi/elo ----------------
__global__ __launch_bounds__(256) void split_e(const float* __restrict__ cb,
                                               unsigned short* __restrict__ ehi,
                                               unsigned short* __restrict__ elo) {
    const size_t i = ((size_t)blockIdx.x * 256 + threadIdx.x) * 4;
    const float4 v = *(const float4*)(cb + i);
    ushort4 h, l;
    h.x = f2bf(v.x); l.x = f2bf(v.x - __uint_as_float((unsigned)h.x << 16));
    h.y = f2bf(v.y); l.y = f2bf(v.y - __uint_as_float((unsigned)h.y << 16));
    h.z = f2bf(v.z); l.z = f2bf(v.z - __uint_as_float((unsigned)h.z << 16));
    h.w = f2bf(v.w); l.w = f2bf(v.w - __uint_as_float((unsigned)h.w << 16));
    *(ushort4*)(ehi + i) = h;
    *(ushort4*)(elo + i) = l;
}

// ------------- numpy pairwise_sum(x*x) over 256 contiguous floats -------------
__global__ __launch_bounds__(256) void row_norms_np(const float* __restrict__ x,
                                                    float* __restrict__ out) {
    const int row = blockIdx.x * 256 + threadIdx.x;
    const float* p = x + (size_t)row * DIM;
    float half_[2];
    #pragma unroll
    for (int h = 0; h < 2; ++h) {
        const float* q = p + h * 128;
        float r[8];
        #pragma unroll
        for (int j = 0; j < 8; j++) r[j] = fm(q[j], q[j]);
        #pragma unroll
        for (int i = 8; i < 128; i += 8)
            #pragma unroll
            for (int j = 0; j < 8; j++) r[j] = fa(r[j], fm(q[i + j], q[i + j]));
        half_[h] = fa(fa(fa(r[0], r[1]), fa(r[2], r[3])),
                      fa(fa(r[4], r[5]), fa(r[6], r[7])));
    }
    out[row] = fa(half_[0], half_[1]);
}

// ------------- same, over a strided z row: element c at z[b][c][hw] -------------
__global__ __launch_bounds__(256) void znorm_np_z(const float* __restrict__ z,
                                                  float* __restrict__ out) {
    const int row = blockIdx.x * 256 + threadIdx.x;
    const float* p = z + ((size_t)(row >> 10) * 256) * 1024 + (row & 1023);
    float half_[2];
    #pragma unroll
    for (int h = 0; h < 2; ++h) {
        const int c0 = h * 128;
        float r[8], v;
        #pragma unroll
        for (int j = 0; j < 8; j++) { v = p[(size_t)(c0 + j) << 10]; r[j] = fm(v, v); }
        #pragma unroll
        for (int i = 8; i < 128; i += 8)
            #pragma unroll
            for (int j = 0; j < 8; j++) {
                v = p[(size_t)(c0 + i + j) << 10];
                r[j] = fa(r[j], fm(v, v));
            }
        half_[h] = fa(fa(fa(r[0], r[1]), fa(r[2], r[3])),
                      fa(fa(r[4], r[5]), fa(r[6], r[7])));
    }
    out[row] = fa(half_[0], half_[1]);
}

// sorted-triple merge: (a,b sorted ascending) -> top-3 of union in a
__device__ __forceinline__ void merge3(unsigned& a0, unsigned& a1, unsigned& a2,
                                       unsigned b0, unsigned b1, unsigned b2) {
    const unsigned m0 = min(a0, b0);
    const unsigned x  = max(a0, b0);
    const unsigned p  = min(a1, b1);
    const unsigned q  = max(a1, b1);
    const unsigned m1 = min(x, p);
    const unsigned m2 = min(max(x, p), min(q, min(a2, b2)));
    a0 = m0; a1 = m1; a2 = m2;
}

// ---------------- MFMA GEMM (K=512) + per-row running top-3 keys ----------------
// grid (128 row-tiles, 32 col-groups of 512); block 256 = 4 waves (2x2 of 64x64)
__global__ __launch_bounds__(256, 3) void gemm_top3(
    const unsigned short* __restrict__ zhi,
    const unsigned short* __restrict__ ehi, const unsigned short* __restrict__ elo,
    const float* __restrict__ en, unsigned* __restrict__ part)
{
    __shared__ unsigned short Ab[128 * 64];   // [m][g'] g' = g ^ (m&7), 16B groups
    __shared__ unsigned short B0[128 * 64];   // ehi tile
    __shared__ unsigned short B1[128 * 64];   // elo tile
    __shared__ unsigned mbuf[128 * 2 * 3];

    const int t = threadIdx.x;
    const int lane = t & 63, w = t >> 6;
    const int wr = w >> 1, wc = w & 1;
    const int q4 = lane >> 4, c4 = lane & 15;
    const int m0 = blockIdx.x * 128;
    const int g0 = blockIdx.y * 512;

    unsigned trip[16][3];                     // running sorted top-3 per (i,r)
    #pragma unroll
    for (int s = 0; s < 16; ++s)
        trip[s][0] = trip[s][1] = trip[s][2] = 0xFFFFFFFFu;

    for (int sub = 0; sub < 4; ++sub) {
        const int n0 = g0 + sub * 128;
        floatx4 acc[4][4];
        #pragma unroll
        for (int i = 0; i < 4; i++)
            #pragma unroll
            for (int j = 0; j < 4; j++) acc[i][j] = (floatx4){0.f, 0.f, 0.f, 0.f};

        for (int kb4 = 0; kb4 < 4; ++kb4) {
            const int kb = kb4 * 64;
            #pragma unroll
            for (int p = 0; p < 4; ++p) {
                const int s   = p * 256 + t;
                const int m   = s >> 3;
                const int g   = (s & 7) ^ (m & 7);
                *(int4*)&Ab[(size_t)s * 8] =
                    *(const int4*)(zhi + (size_t)(m0 + m) * 256 + kb + g * 8);
                *(int4*)&B0[(size_t)s * 8] =
                    *(const int4*)(ehi + (size_t)(n0 + m) * 256 + kb + g * 8);
                *(int4*)&B1[(size_t)s * 8] =
                    *(const int4*)(elo + (size_t)(n0 + m) * 256 + kb + g * 8);
            }
            __syncthreads();
            #pragma unroll
            for (int kk = 0; kk < 2; ++kk) {
                short8 a[4], b0[4], b1[4];
                #pragma unroll
                for (int i = 0; i < 4; ++i) {
                    const int m  = wr * 64 + i * 16 + c4;
                    const int gs = (kk * 4 + q4) ^ (m & 7);
                    a[i] = *(const short8*)&Ab[(size_t)(m * 8 + gs) * 8];
                }
                #pragma unroll
                for (int j = 0; j < 4; ++j) {
                    const int n  = wc * 64 + j * 16 + c4;
                    const int gs = (kk * 4 + q4) ^ (n & 7);
                    b0[j] = *(const short8*)&B0[(size_t)(n * 8 + gs) * 8];
                    b1[j] = *(const short8*)&B1[(size_t)(n * 8 + gs) * 8];
                }
                #pragma unroll
                for (int i = 0; i < 4; ++i)
                    #pragma unroll
                    for (int j = 0; j < 4; ++j)
                        acc[i][j] = __builtin_amdgcn_mfma_f32_16x16x32_bf16(
                            a[i], b0[j], acc[i][j], 0, 0, 0);
                #pragma unroll
                for (int i = 0; i < 4; ++i)
                    #pragma unroll
                    for (int j = 0; j < 4; ++j)
                        acc[i][j] = __builtin_amdgcn_mfma_f32_16x16x32_bf16(
                            a[i], b1[j], acc[i][j], 0, 0, 0);
            }
            __syncthreads();
        }

        // ---- epilogue: 3-op keys + running top-3 (no cross-lane work here) ----
        float en2[4]; unsigned cp[4];
        #pragma unroll
        for (int j = 0; j < 4; ++j) {
            const int col = n0 + wc * 64 + j * 16 + c4;
            en2[j] = en[col] * 1048576.0f;                 // en * 2^20
            cp[j]  = (131072u << 14) + (unsigned)col;
        }
        #pragma unroll
        for (int i = 0; i < 4; ++i)
            #pragma unroll
            for (int r = 0; r < 4; ++r) {
                unsigned k0, k1, k2, k3;
                {   // score*2^20 = fma(acc, -2*2^20, en*2^20); trunc is monotone
                    const int v0 = (int)__builtin_fmaf(acc[i][0][r], -2097152.0f, en2[0]);
                    const int v1 = (int)__builtin_fmaf(acc[i][1][r], -2097152.0f, en2[1]);
                    const int v2 = (int)__builtin_fmaf(acc[i][2][r], -2097152.0f, en2[2]);
                    const int v3 = (int)__builtin_fmaf(acc[i][3][r], -2097152.0f, en2[3]);
                    k0 = ((unsigned)v0 << 14) + cp[0];
                    k1 = ((unsigned)v1 << 14) + cp[1];
                    k2 = ((unsigned)v2 << 14) + cp[2];
                    k3 = ((unsigned)v3 << 14) + cp[3];
                }
                const unsigned l01 = min(k0, k1), h01 = max(k0, k1);
                const unsigned l23 = min(k2, k3), h23 = max(k2, k3);
                const unsigned s0  = min(l01, l23);
                const unsigned m1  = max(l01, l23), m2 = min(h01, h23);
                const unsigned s1  = min(m1, m2),  s2 = max(m1, m2);
                merge3(trip[i * 4 + r][0], trip[i * 4 + r][1], trip[i * 4 + r][2],
                       s0, s1, s2);
            }
    }

    // ---- one cross-lane merge over c4 lanes (masks 1,2,4,8) ----
    #pragma unroll
    for (int s = 0; s < 16; ++s) {
        unsigned t0 = trip[s][0], t1 = trip[s][1], t2 = trip[s][2];
        #pragma unroll
        for (int msk = 1; msk < 16; msk <<= 1) {
            const unsigned u0 = (unsigned)__shfl_xor((int)t0, msk, 64);
            const unsigned u1 = (unsigned)__shfl_xor((int)t1, msk, 64);
            const unsigned u2 = (unsigned)__shfl_xor((int)t2, msk, 64);
            merge3(t0, t1, t2, u0, u1, u2);
        }
        if (c4 < 3) {
            const int row = wr * 64 + (s >> 2) * 16 + q4 * 4 + (s & 3);
            mbuf[(row * 2 + wc) * 3 + c4] = (c4 == 0) ? t0 : ((c4 == 1) ? t1 : t2);
        }
    }
    __syncthreads();
    if (t < 128) {
        unsigned a0 = mbuf[(t * 2 + 0) * 3 + 0];
        unsigned a1 = mbuf[(t * 2 + 0) * 3 + 1];
        unsigned a2 = mbuf[(t * 2 + 0) * 3 + 2];
        merge3(a0, a1, a2, mbuf[(t * 2 + 1) * 3 + 0],
               mbuf[(t * 2 + 1) * 3 + 1], mbuf[(t * 2 + 1) * 3 + 2]);
        unsigned* pp = part + (size_t)(m0 + t) * 96 + blockIdx.y * 3;
        pp[0] = a0; pp[1] = a1; pp[2] = a2;
    }
}

// ---------------- resolve: window-candidates -> exact numpy re-score ----------------
__global__ __launch_bounds__(256) void resolve(
    const unsigned* __restrict__ part, const float* __restrict__ z,
    const float* __restrict__ cb, const float* __restrict__ zn,
    const float* __restrict__ en, float* __restrict__ out_zq,
    float* __restrict__ out_idx)
{
    const int w = threadIdx.x >> 6, lane = threadIdx.x & 63;
    const int row = blockIdx.x * 4 + w;
    __shared__ unsigned candbuf[4][16];

    const unsigned* pr = part + (size_t)row * 96;
    const unsigned k1 = pr[lane];
    const unsigned k2 = (lane < 32) ? pr[64 + lane] : 0xFFFFFFFFu;
    unsigned vm = min(k1, k2);
    #pragma unroll
    for (int m = 1; m < 64; m <<= 1)
        vm = min(vm, (unsigned)__shfl_xor((int)vm, m, 64));
    const unsigned vlim = (vm >> 14) + 84u;
    const bool s1 = (k1 >> 14) <= vlim;
    const bool s2 = (lane < 32) && ((k2 >> 14) <= vlim);
    const unsigned long long b1 = __ballot(s1);
    const unsigned long long b2 = __ballot(s2);
    const unsigned long long below = (1ull << lane) - 1ull;
    const int pos1 = __popcll(b1 & below);
    const int pos2 = __popcll(b1) + __popcll(b2 & below);
    int ncand = __popcll(b1) + __popcll(b2);
    if (ncand > 16) ncand = 16;

    if (lane < 16) candbuf[w][lane] = 0;
    __syncthreads();
    if (s1 && pos1 < 16) candbuf[w][pos1] = k1 & 16383u;
    if (s2 && pos2 < 16) candbuf[w][pos2] = k2 & 16383u;
    __syncthreads();

    const int ci = lane >> 2, l = lane & 3;
    const bool act = ci < ncand;
    const unsigned idxc = candbuf[w][ci];
    const float* zb  = z + ((size_t)(row >> 10) * 256) * 1024 + (row & 1023);
    const float* cbr = cb + (size_t)idxc * 256;
    // numpy einsum SSE chain, lane l of 4: elements ch*16 + v*4 + l, v desc
    float s = 0.f;
    #pragma unroll
    for (int ch = 0; ch < 16; ++ch)
        #pragma unroll
        for (int v = 3; v >= 0; --v) {
            const int cd = ch * 16 + v * 4 + l;
            s = fa(fm(zb[(size_t)cd << 10], cbr[cd]), s);
        }
    const int base = lane & ~3;
    const float s0 = __shfl(s, base + 0, 64);
    const float sA = __shfl(s, base + 1, 64);
    const float sB = __shfl(s, base + 2, 64);
    const float sC = __shfl(s, base + 3, 64);
    const float cross = fa(fa(s0, sA), fa(sB, sC));
    const float d = fs(fa(zn[row], en[idxc]), fm(2.0f, cross));
    unsigned long long key = act
        ? (((unsigned long long)__float_as_uint(d) << 32) | idxc) : ~0ull;
    #pragma unroll
    for (int m = 1; m < 64; m <<= 1) {
        const unsigned long long o =
            (unsigned long long)__shfl_xor((long long)key, m, 64);
        if (o < key) key = o;
    }
    const int widx = (int)(key & 0xFFFFFFFFu);
    *(float4*)(out_zq + (size_t)row * 256 + lane * 4) =
        *(const float4*)(cb + (size_t)widx * 256 + lane * 4);
    if (lane == 0) out_idx[row] = (float)widx;
}

extern "C" void kernel_launch(void* const* d_in, const int* in_sizes, int n_in,
                              void* d_out, int out_size, void* d_ws, size_t ws_size,
                              hipStream_t stream) {
    const float* z  = (const float*)d_in[0];   // [16][256][32][32]
    const float* cb = (const float*)d_in[1];   // [16384][256]
    float* out = (float*)d_out;                // z_q (4194304 f32) then idx (16384 as f32)

    char* ws = (char*)d_ws;
    unsigned short* zhi = (unsigned short*)ws;                        // 8 MB
    unsigned short* ehi = (unsigned short*)(ws + (size_t)8388608);    // 8 MB
    unsigned short* elo = (unsigned short*)(ws + (size_t)16777216);   // 8 MB
    float* zn  = (float*)(ws + (size_t)25165824);                     // 64 KB
    float* en  = (float*)(ws + (size_t)25231360);                     // 64 KB
    unsigned* part = (unsigned*)(ws + (size_t)25296896);              // 6.29 MB

    split_z<<<dim3(32, 8, 16), dim3(32, 8), 0, stream>>>(z, zhi);
    split_e<<<4096, 256, 0, stream>>>(cb, ehi, elo);
    znorm_np_z<<<NQ / 256, 256, 0, stream>>>(z, zn);
    row_norms_np<<<NE / 256, 256, 0, stream>>>(cb, en);
    gemm_top3<<<dim3(128, 32), 256, 0, stream>>>(zhi, ehi, elo, en, part);
    resolve<<<4096, 256, 0, stream>>>(part, z, cb, zn, en, out,
                                      out + (size_t)NQ * DIM);
}

// Round 5
// 439.564 us; speedup vs baseline: 4.4904x; 1.5382x over previous
//
#include <hip/hip_runtime.h>

// VQ nearest-codebook. Reference = numpy float32 pipeline (verified bit-exact
// R2). fp16 MFMA GEMM (K=256): s*2^20 = en*2^20 - 128*acc, where
// acc = fp16(z).fp16(e*2^14) accumulated fp32 (score error sigma ~3e-7,
// far below the 84-unit resolve window). Per-row running top-3 keys per
// 512-col group, exact numpy-f32 re-score of window candidates.
//
// ws: zh 8MB | eh 8MB | zn 64K | en 64K | part 6.3MB

#define NQ 16384
#define NE 16384
#define DIM 256

typedef __attribute__((ext_vector_type(8))) _Float16 half8;
typedef __attribute__((ext_vector_type(4))) float floatx4;

__device__ __forceinline__ float fm(float a, float b) { return __fmul_rn(a, b); }
__device__ __forceinline__ float fa(float a, float b) { return __fadd_rn(a, b); }
__device__ __forceinline__ float fs(float a, float b) { return __fsub_rn(a, b); }

#define GLOAD_LDS16(gp, lp)                                                  \
    __builtin_amdgcn_global_load_lds(                                        \
        (const __attribute__((address_space(1))) void*)(gp),                 \
        (__attribute__((address_space(3))) void*)(lp), 16, 0, 0)

// ---------- transpose z[b][c][hw] -> zh[(b*1024+hw)][c] (fp16) ----------
__global__ void split_z(const float* __restrict__ z, _Float16* __restrict__ zh) {
    __shared__ float tile[32][33];
    const int b  = blockIdx.z;
    const int c0 = blockIdx.y * 32;
    const int n0 = blockIdx.x * 32;
    const int tx = threadIdx.x, ty = threadIdx.y;   // 32 x 8
    const float* zb = z + (size_t)b * 256 * 1024;
    #pragma unroll
    for (int j = 0; j < 32; j += 8)
        tile[ty + j][tx] = zb[(size_t)(c0 + ty + j) * 1024 + n0 + tx];
    __syncthreads();
    #pragma unroll
    for (int j = 0; j < 32; j += 8)
        zh[(size_t)(b * 1024 + n0 + ty + j) * 256 + c0 + tx] =
            (_Float16)tile[tx][ty + j];
}

// ---------------- codebook -> fp16(e * 2^14) ----------------
__global__ __launch_bounds__(256) void split_e(const float* __restrict__ cb,
                                               _Float16* __restrict__ eh) {
    const size_t i = ((size_t)blockIdx.x * 256 + threadIdx.x) * 4;
    const float4 v = *(const float4*)(cb + i);
    _Float16 o[4] = { (_Float16)(v.x * 16384.0f), (_Float16)(v.y * 16384.0f),
                      (_Float16)(v.z * 16384.0f), (_Float16)(v.w * 16384.0f) };
    *(ushort4*)(eh + i) = *(const ushort4*)o;
}

// ------------- numpy pairwise_sum(x*x) over 256 contiguous floats -------------
__global__ __launch_bounds__(256) void row_norms_np(const float* __restrict__ x,
                                                    float* __restrict__ out) {
    const int row = blockIdx.x * 256 + threadIdx.x;
    const float* p = x + (size_t)row * DIM;
    float half_[2];
    #pragma unroll
    for (int h = 0; h < 2; ++h) {
        const float* q = p + h * 128;
        float r[8];
        #pragma unroll
        for (int j = 0; j < 8; j++) r[j] = fm(q[j], q[j]);
        #pragma unroll
        for (int i = 8; i < 128; i += 8)
            #pragma unroll
            for (int j = 0; j < 8; j++) r[j] = fa(r[j], fm(q[i + j], q[i + j]));
        half_[h] = fa(fa(fa(r[0], r[1]), fa(r[2], r[3])),
                      fa(fa(r[4], r[5]), fa(r[6], r[7])));
    }
    out[row] = fa(half_[0], half_[1]);
}

// ------------- same, over a strided z row: element c at z[b][c][hw] -------------
__global__ __launch_bounds__(256) void znorm_np_z(const float* __restrict__ z,
                                                  float* __restrict__ out) {
    const int row = blockIdx.x * 256 + threadIdx.x;
    const float* p = z + ((size_t)(row >> 10) * 256) * 1024 + (row & 1023);
    float half_[2];
    #pragma unroll
    for (int h = 0; h < 2; ++h) {
        const int c0 = h * 128;
        float r[8], v;
        #pragma unroll
        for (int j = 0; j < 8; j++) { v = p[(size_t)(c0 + j) << 10]; r[j] = fm(v, v); }
        #pragma unroll
        for (int i = 8; i < 128; i += 8)
            #pragma unroll
            for (int j = 0; j < 8; j++) {
                v = p[(size_t)(c0 + i + j) << 10];
                r[j] = fa(r[j], fm(v, v));
            }
        half_[h] = fa(fa(fa(r[0], r[1]), fa(r[2], r[3])),
                      fa(fa(r[4], r[5]), fa(r[6], r[7])));
    }
    out[row] = fa(half_[0], half_[1]);
}

// sorted-triple merge: (a,b sorted ascending) -> top-3 of union in a
__device__ __forceinline__ void merge3(unsigned& a0, unsigned& a1, unsigned& a2,
                                       unsigned b0, unsigned b1, unsigned b2) {
    const unsigned m0 = min(a0, b0);
    const unsigned x  = max(a0, b0);
    const unsigned p  = min(a1, b1);
    const unsigned q  = max(a1, b1);
    const unsigned m1 = min(x, p);
    const unsigned m2 = min(max(x, p), min(q, min(a2, b2)));
    a0 = m0; a1 = m1; a2 = m2;
}

// ---------------- MFMA GEMM (K=256 fp16) + per-row running top-3 keys ----------------
// grid (128 row-tiles, 32 col-groups of 512); block 256 = 4 waves (2x2 of 64x64)
__global__ __launch_bounds__(256, 3) void gemm_top3(
    const _Float16* __restrict__ zh, const _Float16* __restrict__ eh,
    const float* __restrict__ en, unsigned* __restrict__ part)
{
    __shared__ __align__(16) _Float16 Ab[128 * 64];  // [m][g'] g' = g ^ (m&7), 16B groups
    __shared__ __align__(16) _Float16 Bb[128 * 64];
    __shared__ unsigned mbuf[128 * 2 * 3];

    const int t = threadIdx.x;
    const int lane = t & 63, w = t >> 6;
    const int wr = w >> 1, wc = w & 1;
    const int q4 = lane >> 4, c4 = lane & 15;
    const int m0 = blockIdx.x * 128;
    const int g0 = blockIdx.y * 512;

    unsigned trip[16][3];                     // running sorted top-3 per (i,r)
    #pragma unroll
    for (int s = 0; s < 16; ++s)
        trip[s][0] = trip[s][1] = trip[s][2] = 0xFFFFFFFFu;

    // per-thread DMA slot geometry (constant across iterations)
    const int sm[4] = { (0 * 256 + t) >> 3, (1 * 256 + t) >> 3,
                        (2 * 256 + t) >> 3, (3 * 256 + t) >> 3 };
    const int sg[4] = { (t & 7) ^ (sm[0] & 7), (t & 7) ^ (sm[1] & 7),
                        (t & 7) ^ (sm[2] & 7), (t & 7) ^ (sm[3] & 7) };
    const int ldsb = w * 64 * 8;              // wave-uniform LDS slot base (elements)

    for (int sub = 0; sub < 4; ++sub) {
        const int n0 = g0 + sub * 128;
        floatx4 acc[4][4];
        #pragma unroll
        for (int i = 0; i < 4; i++)
            #pragma unroll
            for (int j = 0; j < 4; j++) acc[i][j] = (floatx4){0.f, 0.f, 0.f, 0.f};

        for (int kb4 = 0; kb4 < 4; ++kb4) {
            const int kb = kb4 * 64;
            #pragma unroll
            for (int p = 0; p < 4; ++p) {
                GLOAD_LDS16(zh + (size_t)(m0 + sm[p]) * 256 + kb + sg[p] * 8,
                            &Ab[(p * 256) * 8 + ldsb]);
                GLOAD_LDS16(eh + (size_t)(n0 + sm[p]) * 256 + kb + sg[p] * 8,
                            &Bb[(p * 256) * 8 + ldsb]);
            }
            __syncthreads();
            #pragma unroll
            for (int kk = 0; kk < 2; ++kk) {
                half8 a[4], b[4];
                #pragma unroll
                for (int i = 0; i < 4; ++i) {
                    const int m  = wr * 64 + i * 16 + c4;
                    const int gs = (kk * 4 + q4) ^ (m & 7);
                    a[i] = *(const half8*)&Ab[(size_t)(m * 8 + gs) * 8];
                }
                #pragma unroll
                for (int j = 0; j < 4; ++j) {
                    const int n  = wc * 64 + j * 16 + c4;
                    const int gs = (kk * 4 + q4) ^ (n & 7);
                    b[j] = *(const half8*)&Bb[(size_t)(n * 8 + gs) * 8];
                }
                #pragma unroll
                for (int i = 0; i < 4; ++i)
                    #pragma unroll
                    for (int j = 0; j < 4; ++j)
                        acc[i][j] = __builtin_amdgcn_mfma_f32_16x16x32_f16(
                            a[i], b[j], acc[i][j], 0, 0, 0);
            }
            __syncthreads();
        }

        // ---- epilogue: 3-op keys + running top-3 (register-only) ----
        float en2[4]; unsigned cp[4];
        #pragma unroll
        for (int j = 0; j < 4; ++j) {
            const int col = n0 + wc * 64 + j * 16 + c4;
            en2[j] = en[col] * 1048576.0f;                 // en * 2^20
            cp[j]  = (131072u << 14) + (unsigned)col;
        }
        #pragma unroll
        for (int i = 0; i < 4; ++i)
            #pragma unroll
            for (int r = 0; r < 4; ++r) {
                // s*2^20 = en*2^20 - 2*2^-14*2^20*acc = fma(acc,-128,en2)
                const int v0 = (int)__builtin_fmaf(acc[i][0][r], -128.0f, en2[0]);
                const int v1 = (int)__builtin_fmaf(acc[i][1][r], -128.0f, en2[1]);
                const int v2 = (int)__builtin_fmaf(acc[i][2][r], -128.0f, en2[2]);
                const int v3 = (int)__builtin_fmaf(acc[i][3][r], -128.0f, en2[3]);
                const unsigned k0 = ((unsigned)v0 << 14) + cp[0];
                const unsigned k1 = ((unsigned)v1 << 14) + cp[1];
                const unsigned k2 = ((unsigned)v2 << 14) + cp[2];
                const unsigned k3 = ((unsigned)v3 << 14) + cp[3];
                const unsigned l01 = min(k0, k1), h01 = max(k0, k1);
                const unsigned l23 = min(k2, k3), h23 = max(k2, k3);
                const unsigned s0  = min(l01, l23);
                const unsigned m1  = max(l01, l23), m2 = min(h01, h23);
                const unsigned s1  = min(m1, m2),  s2 = max(m1, m2);
                merge3(trip[i * 4 + r][0], trip[i * 4 + r][1], trip[i * 4 + r][2],
                       s0, s1, s2);
            }
    }

    // ---- one cross-lane merge over c4 lanes (masks 1,2,4,8) ----
    #pragma unroll
    for (int s = 0; s < 16; ++s) {
        unsigned t0 = trip[s][0], t1 = trip[s][1], t2 = trip[s][2];
        #pragma unroll
        for (int msk = 1; msk < 16; msk <<= 1) {
            const unsigned u0 = (unsigned)__shfl_xor((int)t0, msk, 64);
            const unsigned u1 = (unsigned)__shfl_xor((int)t1, msk, 64);
            const unsigned u2 = (unsigned)__shfl_xor((int)t2, msk, 64);
            merge3(t0, t1, t2, u0, u1, u2);
        }
        if (c4 < 3) {
            const int row = wr * 64 + (s >> 2) * 16 + q4 * 4 + (s & 3);
            mbuf[(row * 2 + wc) * 3 + c4] = (c4 == 0) ? t0 : ((c4 == 1) ? t1 : t2);
        }
    }
    __syncthreads();
    if (t < 128) {
        unsigned a0 = mbuf[(t * 2 + 0) * 3 + 0];
        unsigned a1 = mbuf[(t * 2 + 0) * 3 + 1];
        unsigned a2 = mbuf[(t * 2 + 0) * 3 + 2];
        merge3(a0, a1, a2, mbuf[(t * 2 + 1) * 3 + 0],
               mbuf[(t * 2 + 1) * 3 + 1], mbuf[(t * 2 + 1) * 3 + 2]);
        unsigned* pp = part + (size_t)(m0 + t) * 96 + blockIdx.y * 3;
        pp[0] = a0; pp[1] = a1; pp[2] = a2;
    }
}

// ---------------- resolve: window-candidates -> exact numpy re-score ----------------
__global__ __launch_bounds__(256) void resolve(
    const unsigned* __restrict__ part, const float* __restrict__ z,
    const float* __restrict__ cb, const float* __restrict__ zn,
    const float* __restrict__ en, float* __restrict__ out_zq,
    float* __restrict__ out_idx)
{
    const int w = threadIdx.x >> 6, lane = threadIdx.x & 63;
    const int row = blockIdx.x * 4 + w;
    __shared__ unsigned candbuf[4][16];

    const unsigned* pr = part + (size_t)row * 96;
    const unsigned k1 = pr[lane];
    const unsigned k2 = (lane < 32) ? pr[64 + lane] : 0xFFFFFFFFu;
    unsigned vm = min(k1, k2);
    #pragma unroll
    for (int m = 1; m < 64; m <<= 1)
        vm = min(vm, (unsigned)__shfl_xor((int)vm, m, 64));
    const unsigned vlim = (vm >> 14) + 84u;
    const bool s1 = (k1 >> 14) <= vlim;
    const bool s2 = (lane < 32) && ((k2 >> 14) <= vlim);
    const unsigned long long b1 = __ballot(s1);
    const unsigned long long b2 = __ballot(s2);
    const unsigned long long below = (1ull << lane) - 1ull;
    const int pos1 = __popcll(b1 & below);
    const int pos2 = __popcll(b1) + __popcll(b2 & below);
    int ncand = __popcll(b1) + __popcll(b2);
    if (ncand > 16) ncand = 16;

    if (lane < 16) candbuf[w][lane] = 0;
    __syncthreads();
    if (s1 && pos1 < 16) candbuf[w][pos1] = k1 & 16383u;
    if (s2 && pos2 < 16) candbuf[w][pos2] = k2 & 16383u;
    __syncthreads();

    const int ci = lane >> 2, l = lane & 3;
    const bool act = ci < ncand;
    const unsigned idxc = candbuf[w][ci];
    const float* zb  = z + ((size_t)(row >> 10) * 256) * 1024 + (row & 1023);
    const float* cbr = cb + (size_t)idxc * 256;
    // numpy einsum SSE chain, lane l of 4: elements ch*16 + v*4 + l, v desc
    float s = 0.f;
    #pragma unroll
    for (int ch = 0; ch < 16; ++ch)
        #pragma unroll
        for (int v = 3; v >= 0; --v) {
            const int cd = ch * 16 + v * 4 + l;
            s = fa(fm(zb[(size_t)cd << 10], cbr[cd]), s);
        }
    const int base = lane & ~3;
    const float s0 = __shfl(s, base + 0, 64);
    const float sA = __shfl(s, base + 1, 64);
    const float sB = __shfl(s, base + 2, 64);
    const float sC = __shfl(s, base + 3, 64);
    const float cross = fa(fa(s0, sA), fa(sB, sC));
    const float d = fs(fa(zn[row], en[idxc]), fm(2.0f, cross));
    unsigned long long key = act
        ? (((unsigned long long)__float_as_uint(d) << 32) | idxc) : ~0ull;
    #pragma unroll
    for (int m = 1; m < 64; m <<= 1) {
        const unsigned long long o =
            (unsigned long long)__shfl_xor((long long)key, m, 64);
        if (o < key) key = o;
    }
    const int widx = (int)(key & 0xFFFFFFFFu);
    *(float4*)(out_zq + (size_t)row * 256 + lane * 4) =
        *(const float4*)(cb + (size_t)widx * 256 + lane * 4);
    if (lane == 0) out_idx[row] = (float)widx;
}

extern "C" void kernel_launch(void* const* d_in, const int* in_sizes, int n_in,
                              void* d_out, int out_size, void* d_ws, size_t ws_size,
                              hipStream_t stream) {
    const float* z  = (const float*)d_in[0];   // [16][256][32][32]
    const float* cb = (const float*)d_in[1];   // [16384][256]
    float* out = (float*)d_out;                // z_q (4194304 f32) then idx (16384 as f32)

    char* ws = (char*)d_ws;
    _Float16* zh = (_Float16*)ws;                                  // 8 MB
    _Float16* eh = (_Float16*)(ws + (size_t)8388608);              // 8 MB
    float* zn  = (float*)(ws + (size_t)16777216);                  // 64 KB
    float* en  = (float*)(ws + (size_t)16842752);                  // 64 KB
    unsigned* part = (unsigned*)(ws + (size_t)16908288);           // 6.29 MB

    split_z<<<dim3(32, 8, 16), dim3(32, 8), 0, stream>>>(z, zh);
    split_e<<<4096, 256, 0, stream>>>(cb, eh);
    znorm_np_z<<<NQ / 256, 256, 0, stream>>>(z, zn);
    row_norms_np<<<NE / 256, 256, 0, stream>>>(cb, en);
    gemm_top3<<<dim3(128, 32), 256, 0, stream>>>(zh, eh, en, part);
    resolve<<<4096, 256, 0, stream>>>(part, z, cb, zn, en, out,
                                      out + (size_t)NQ * DIM);
}